// Round 12
// baseline (1168.098 us; speedup 1.0000x reference)
//
#include <hip/hip_runtime.h>
#include <hip/hip_bf16.h>

#define NN 50000
#define NE 600000
#define HD 128
#define DET_SAMPLES 65536
#define NBLK 196                     // ceil((NN+1)/256)

typedef unsigned short ushort_t;

__device__ __forceinline__ float sigmoidf_(float x){ return 1.f/(1.f+__expf(-x)); }

__device__ __forceinline__ ushort_t f2bf(float f){
  unsigned int u = __float_as_uint(f);
  unsigned int r = (u + 0x7FFFu + ((u >> 16) & 1u)) >> 16;   // RNE
  return (ushort_t)r;
}

__device__ __forceinline__ float bflo(unsigned u){ return __uint_as_float(u << 16); }
__device__ __forceinline__ float bfhi(unsigned u){ return __uint_as_float(u & 0xFFFF0000u); }

// ---------------- diagnostic scalar write (env tripwire) ----------------
__global__ void write_scalar_kernel(float* __restrict__ p, float v){ p[0] = v; }

// ---------------- edge_index dtype detect + decode (+ dst histogram) ----------------
__global__ void detect_kernel(const unsigned int* __restrict__ w, int* __restrict__ flag){
  int i = blockIdx.x*256 + threadIdx.x;           // [0, DET_SAMPLES)
  int z = (w[2*i + 1] == 0u) ? 1 : 0;
  atomicAdd(flag, z);
}

__global__ void extract_kernel(const void* __restrict__ ei, const int* __restrict__ flag,
                               int* __restrict__ srcW, int* __restrict__ dstW,
                               int* __restrict__ counts){
  const int e = blockIdx.x*256 + threadIdx.x;
  if (e >= NE) return;
  int s, d;
  if (*flag > (DET_SAMPLES/2)){
    const long long* p = (const long long*)ei;
    s = (int)p[e]; d = (int)p[NE + e];
  } else {
    const int* p = (const int*)ei;
    s = p[e]; d = p[NE + e];
  }
  srcW[e] = s; dstW[e] = d;
  atomicAdd(&counts[d], 1);
}

// ---------------- hierarchical exclusive scan of counts[NN] ----------------
__global__ __launch_bounds__(256) void scanA_kernel(const int* __restrict__ counts,
                                                    int* __restrict__ partial){
  __shared__ int s[256];
  const int t = threadIdx.x;
  const int idx = blockIdx.x*256 + t;
  s[t] = (idx < NN) ? counts[idx] : 0;
  __syncthreads();
  for (int off = 128; off > 0; off >>= 1){
    if (t < off) s[t] += s[t + off];
    __syncthreads();
  }
  if (t == 0) partial[blockIdx.x] = s[0];
}

__global__ __launch_bounds__(256) void scanB_kernel(const int* __restrict__ partial,
                                                    int* __restrict__ bOff){
  __shared__ int s[256];
  const int t = threadIdx.x;
  const int v = (t < NBLK) ? partial[t] : 0;
  s[t] = v;
  __syncthreads();
  for (int off = 1; off < 256; off <<= 1){
    int add = (t >= off) ? s[t - off] : 0;
    __syncthreads();
    s[t] += add;
    __syncthreads();
  }
  if (t < NBLK) bOff[t] = s[t] - v;        // exclusive
}

__global__ __launch_bounds__(256) void scanC_kernel(const int* __restrict__ counts,
    const int* __restrict__ bOff, int* __restrict__ row_start, int* __restrict__ cursor){
  __shared__ int s[256];
  const int t = threadIdx.x;
  const int idx = blockIdx.x*256 + t;
  const int c = (idx < NN) ? counts[idx] : 0;
  s[t] = c;
  __syncthreads();
  for (int off = 1; off < 256; off <<= 1){
    int add = (t >= off) ? s[t - off] : 0;
    __syncthreads();
    s[t] += add;
    __syncthreads();
  }
  const int excl = bOff[blockIdx.x] + s[t] - c;
  if (idx < NN){ row_start[idx] = excl; cursor[idx] = excl; }
  else if (idx == NN){ row_start[NN] = excl; }
}

__global__ void fill_kernel(const int* __restrict__ dstI, int* __restrict__ cursor,
                            int* __restrict__ eids){
  int e = blockIdx.x*256 + threadIdx.x;
  if (e < NE){ int p = atomicAdd(&cursor[dstI[e]], 1); eids[p] = e; }
}

// ---------------- GEMM: act(in @ W + bias) -> optional f32 out + optional bf16 out ----
__global__ __launch_bounds__(256) void gemm128(const float* __restrict__ in,
    const float* __restrict__ W, const float* __restrict__ bias,
    float* __restrict__ outF, ushort_t* __restrict__ outB, int n, int doRelu)
{
  __shared__ float Ws[HD*HD];
  __shared__ float Is[32*129];
  const int tid = threadIdx.x;
  const float4* W4 = (const float4*)W;
  float4* Ws4 = (float4*)Ws;
  #pragma unroll
  for (int i = 0; i < 16; ++i) Ws4[tid + i*256] = W4[tid + i*256];
  const int row0 = blockIdx.x * 32;
  #pragma unroll
  for (int i = 0; i < 4; ++i){
    int f = tid + i*256;
    int r = f >> 5, c4 = (f & 31) * 4;
    float4 v = make_float4(0.f,0.f,0.f,0.f);
    if (row0 + r < n) v = *(const float4*)(in + (size_t)(row0 + r)*HD + c4);
    float* dp = &Is[r*129 + c4];
    dp[0]=v.x; dp[1]=v.y; dp[2]=v.z; dp[3]=v.w;
  }
  __syncthreads();
  const int rg = tid >> 4;
  const int cg = tid & 15;
  float acc0[8] = {0,0,0,0,0,0,0,0};
  float acc1[8] = {0,0,0,0,0,0,0,0};
  #pragma unroll 4
  for (int k = 0; k < HD; ++k){
    float a0 = Is[rg*129 + k];
    float a1 = Is[(rg+16)*129 + k];
    #pragma unroll
    for (int j = 0; j < 8; ++j){
      float w = Ws[k*HD + cg + 16*j];
      acc0[j] = fmaf(a0, w, acc0[j]);
      acc1[j] = fmaf(a1, w, acc1[j]);
    }
  }
  const int r0 = row0 + rg, r1 = r0 + 16;
  #pragma unroll
  for (int j = 0; j < 8; ++j){
    int c = cg + 16*j;
    float b = bias ? bias[c] : 0.f;
    float x0 = acc0[j] + b, x1 = acc1[j] + b;
    if (doRelu){ x0 = fmaxf(x0, 0.f); x1 = fmaxf(x1, 0.f); }
    if (outF){
      if (r0 < n) outF[(size_t)r0*HD + c] = x0;
      if (r1 < n) outF[(size_t)r1*HD + c] = x1;
    }
    if (outB){
      if (r0 < n) outB[(size_t)r0*HD + c] = f2bf(x0);
      if (r1 < n) outB[(size_t)r1*HD + c] = f2bf(x1);
    }
  }
}

// ---------------- edge mask over bf16 U/V ----------------
__global__ __launch_bounds__(256) void edge_mask_kernel(const ushort_t* __restrict__ U,
    const ushort_t* __restrict__ V, const int* __restrict__ srcI, const int* __restrict__ dstI,
    const float* __restrict__ Wm2, const float* __restrict__ bm2,
    float* __restrict__ maskOut)
{
  const int t = threadIdx.x;
  const int sub = t & 15;                       // 16 lanes/edge, 8 cols/lane
  const int e = blockIdx.x * 16 + (t >> 4);
  const int s = srcI[e], d = dstI[e];
  const uint4 a = ((const uint4*)(U + (size_t)s*HD))[sub];
  const uint4 b = ((const uint4*)(V + (size_t)d*HD))[sub];
  const int c0 = sub * 8;
  float acc = 0.f;
  float x;
  x = fmaxf(bflo(a.x) + bflo(b.x), 0.f); acc = fmaf(x, Wm2[c0+0], acc);
  x = fmaxf(bfhi(a.x) + bfhi(b.x), 0.f); acc = fmaf(x, Wm2[c0+1], acc);
  x = fmaxf(bflo(a.y) + bflo(b.y), 0.f); acc = fmaf(x, Wm2[c0+2], acc);
  x = fmaxf(bfhi(a.y) + bfhi(b.y), 0.f); acc = fmaf(x, Wm2[c0+3], acc);
  x = fmaxf(bflo(a.z) + bflo(b.z), 0.f); acc = fmaf(x, Wm2[c0+4], acc);
  x = fmaxf(bfhi(a.z) + bfhi(b.z), 0.f); acc = fmaf(x, Wm2[c0+5], acc);
  x = fmaxf(bflo(a.w) + bflo(b.w), 0.f); acc = fmaf(x, Wm2[c0+6], acc);
  x = fmaxf(bfhi(a.w) + bfhi(b.w), 0.f); acc = fmaf(x, Wm2[c0+7], acc);
  #pragma unroll
  for (int m = 1; m < 16; m <<= 1) acc += __shfl_xor(acc, m, 64);
  if (sub == 0){
    float imp = sigmoidf_(acc + bm2[0]);
    maskOut[e] = sigmoidf_((imp - 0.4f) * 2.0f);
  }
}

// ---------- message pass: tmp[v] = h[v] + sum mask[e]*hB[src[e]]  (bf16 gather) --------
__global__ __launch_bounds__(256) void msg_kernel(const float* __restrict__ h,
    const ushort_t* __restrict__ hB, const float* __restrict__ mask,
    const int* __restrict__ srcI, const int* __restrict__ row_start,
    const int* __restrict__ eids, float* __restrict__ outp)
{
  const int v = blockIdx.x*4 + (threadIdx.x >> 6);
  const int lane = threadIdx.x & 63;
  float2 acc = ((const float2*)(h + (size_t)v*HD))[lane];
  const int beg = row_start[v], end = row_start[v+1];
  for (int idx = beg; idx < end; ++idx){
    const int e = eids[idx];
    const float m = mask[e];
    const int s = srcI[e];
    const unsigned u = ((const unsigned*)(hB + (size_t)s*HD))[lane];
    acc.x = fmaf(m, bflo(u), acc.x);
    acc.y = fmaf(m, bfhi(u), acc.y);
  }
  ((float2*)(outp + (size_t)v*HD))[lane] = acc;
}

// ---------------- predictor ----------------
__global__ __launch_bounds__(128) void pred_kernel(const float* __restrict__ h,
  const float* __restrict__ Wp1, const float* __restrict__ bp1,
  const float* __restrict__ Wp2, const float* __restrict__ bp2,
  float* __restrict__ out0)
{
  __shared__ float red[128];
  const int t = threadIdx.x;
  float s = bp1[t];
  for (int k = 0; k < HD; ++k) s = fmaf(h[k], Wp1[k*HD + t], s);
  s = fmaxf(s, 0.f) * Wp2[t];
  red[t] = s;
  __syncthreads();
  for (int off = 64; off > 0; off >>= 1){
    if (t < off) red[t] += red[t + off];
    __syncthreads();
  }
  if (t == 0) out0[0] = red[0] + bp2[0];
}

extern "C" void kernel_launch(void* const* d_in, const int* in_sizes, int n_in,
                              void* d_out, int out_size, void* d_ws, size_t ws_size,
                              hipStream_t stream)
{
  (void)out_size;
  float* fOut = (float*)d_out;
  float* predOut = fOut;               // f32[0]
  float* maskOut = fOut + 1;           // f32[1 .. 1+NE)
  float* hOut    = fOut + 1 + NE;      // f32[1+NE ..)

  // ---- env tripwire (clean since R5; kept) ----
  static const int expSizes[14] = {6400000,1200000,16384,128,49152,384,32768,128,128,1,
                                   16384,128,128,1};
  const size_t NEEDED = 87100000;
  float diag = 0.f;
  if (n_in != 14) diag = 900.f + (float)n_in;
  else {
    for (int i = 0; i < 14; ++i)
      if (in_sizes[i] != expSizes[i]){ diag = 200.f + 16.f*(float)i; break; }
  }
  if (diag == 0.f && ws_size < NEEDED) diag = 5000.f + (float)(ws_size >> 20);

  if (diag != 0.f){
    write_scalar_kernel<<<1, 1, 0, stream>>>(predOut, diag);
    return;
  }

  const float* nf   = (const float*)d_in[0];
  const void*  ei   = d_in[1];
  const float* Wemb = (const float*)d_in[2];
  const float* bemb = (const float*)d_in[3];
  const float* Wgnn = (const float*)d_in[4];
  const float* bgnn = (const float*)d_in[5];
  const float* Wm1  = (const float*)d_in[6];
  const float* bm1  = (const float*)d_in[7];
  const float* Wm2  = (const float*)d_in[8];
  const float* bm2  = (const float*)d_in[9];
  const float* Wp1  = (const float*)d_in[10];
  const float* bp1  = (const float*)d_in[11];
  const float* Wp2  = (const float*)d_in[12];
  const float* bp2  = (const float*)d_in[13];

  float* hA    = (float*)d_ws;                        // h f32           (25.6 MB)
  float* tmpU  = hA   + (size_t)NN*HD;                // U(bf16) / h+msg (25.6 MB)
  float* Vbuf  = tmpU + (size_t)NN*HD;                // V(bf16) + hB    (25.6 MB)
  float* maskF = Vbuf + (size_t)NN*HD;                // mask f32        (2.4 MB)
  int* row_start = (int*)(maskF + NE);                // NN+1
  int* cursor  = row_start + (NN + 1);                // NN
  int* counts  = cursor + NN;                         // NN
  int* eids    = counts + NN;                         // NE
  int* srcW    = eids + NE;                           // NE
  int* dstW    = srcW + NE;                           // NE
  int* flag    = dstW + NE;                           // 1
  int* partial = flag + 1;                            // NBLK
  int* bOff    = partial + NBLK;                      // NBLK

  ushort_t* Ub = (ushort_t*)tmpU;                     // bf16 U (first half of tmpU)
  ushort_t* Vb = (ushort_t*)Vbuf;                     // bf16 V (first half of Vbuf)
  ushort_t* hB = (ushort_t*)Vbuf + (size_t)NN*HD;     // bf16 h shadow (second half of Vbuf)

  // --- decode edge_index + dst histogram ---
  hipMemsetAsync(flag, 0, sizeof(int), stream);
  hipMemsetAsync(counts, 0, NN*sizeof(int), stream);
  detect_kernel<<<DET_SAMPLES/256, 256, 0, stream>>>((const unsigned int*)ei, flag);
  extract_kernel<<<(NE + 255)/256, 256, 0, stream>>>(ei, flag, srcW, dstW, counts);

  // --- CSR: hierarchical exclusive scan + fill ---
  scanA_kernel<<<NBLK, 256, 0, stream>>>(counts, partial);
  scanB_kernel<<<1, 256, 0, stream>>>(partial, bOff);
  scanC_kernel<<<NBLK, 256, 0, stream>>>(counts, bOff, row_start, cursor);
  fill_kernel<<<(NE + 255)/256, 256, 0, stream>>>(dstW, cursor, eids);

  const int gGemm = (NN + 31)/32;
  // h = relu(nf@Wemb+bemb): f32 + bf16 shadow
  gemm128<<<gGemm, 256, 0, stream>>>(nf, Wemb, bemb, hA, hB, NN, 1);

  for (int L = 0; L < 3; ++L){
    float* mcur  = (L < 2) ? maskF : maskOut;
    float* hnext = (L < 2) ? hA : hOut;
    ushort_t* hBnext = (L < 2) ? hB : nullptr;        // no msg pass after final layer
    gemm128<<<gGemm, 256, 0, stream>>>(hA, Wm1,         bm1,     nullptr, Ub, NN, 0);
    gemm128<<<gGemm, 256, 0, stream>>>(hA, Wm1 + HD*HD, nullptr, nullptr, Vb, NN, 0);
    edge_mask_kernel<<<NE/16, 256, 0, stream>>>(Ub, Vb, srcW, dstW, Wm2, bm2, mcur);
    msg_kernel<<<NN/4, 256, 0, stream>>>(hA, hB, mcur, srcW, row_start, eids, tmpU);  // clobbers Ub (done)
    gemm128<<<gGemm, 256, 0, stream>>>(tmpU, Wgnn + (size_t)L*HD*HD, bgnn + (size_t)L*HD, hnext, hBnext, NN, 1);
  }

  pred_kernel<<<1, 128, 0, stream>>>(hOut, Wp1, bp1, Wp2, bp2, predOut);
}

// Round 13
// 978.825 us; speedup vs baseline: 1.1934x; 1.1934x over previous
//
#include <hip/hip_runtime.h>
#include <hip/hip_bf16.h>

#define NN 50000
#define NE 600000
#define HD 128
#define DET_SAMPLES 65536
#define NBLK 196                     // ceil((NN+1)/256)

typedef unsigned short ushort_t;

__device__ __forceinline__ float sigmoidf_(float x){ return 1.f/(1.f+__expf(-x)); }

__device__ __forceinline__ ushort_t f2bf(float f){
  unsigned int u = __float_as_uint(f);
  unsigned int r = (u + 0x7FFFu + ((u >> 16) & 1u)) >> 16;   // RNE
  return (ushort_t)r;
}

__device__ __forceinline__ float bflo(unsigned u){ return __uint_as_float(u << 16); }
__device__ __forceinline__ float bfhi(unsigned u){ return __uint_as_float(u & 0xFFFF0000u); }

// ---------------- diagnostic scalar write (env tripwire) ----------------
__global__ void write_scalar_kernel(float* __restrict__ p, float v){ p[0] = v; }

// ---------------- edge_index dtype detect + decode (+ dst histogram) ----------------
__global__ void detect_kernel(const unsigned int* __restrict__ w, int* __restrict__ flag){
  int i = blockIdx.x*256 + threadIdx.x;           // [0, DET_SAMPLES)
  int z = (w[2*i + 1] == 0u) ? 1 : 0;
  atomicAdd(flag, z);
}

__global__ void extract_kernel(const void* __restrict__ ei, const int* __restrict__ flag,
                               int* __restrict__ srcW, int* __restrict__ dstW,
                               int* __restrict__ counts){
  const int e = blockIdx.x*256 + threadIdx.x;
  if (e >= NE) return;
  int s, d;
  if (*flag > (DET_SAMPLES/2)){
    const long long* p = (const long long*)ei;
    s = (int)p[e]; d = (int)p[NE + e];
  } else {
    const int* p = (const int*)ei;
    s = p[e]; d = p[NE + e];
  }
  srcW[e] = s; dstW[e] = d;
  atomicAdd(&counts[d], 1);
}

// ---------------- hierarchical exclusive scan of counts[NN] ----------------
__global__ __launch_bounds__(256) void scanA_kernel(const int* __restrict__ counts,
                                                    int* __restrict__ partial){
  __shared__ int s[256];
  const int t = threadIdx.x;
  const int idx = blockIdx.x*256 + t;
  s[t] = (idx < NN) ? counts[idx] : 0;
  __syncthreads();
  for (int off = 128; off > 0; off >>= 1){
    if (t < off) s[t] += s[t + off];
    __syncthreads();
  }
  if (t == 0) partial[blockIdx.x] = s[0];
}

__global__ __launch_bounds__(256) void scanB_kernel(const int* __restrict__ partial,
                                                    int* __restrict__ bOff){
  __shared__ int s[256];
  const int t = threadIdx.x;
  const int v = (t < NBLK) ? partial[t] : 0;
  s[t] = v;
  __syncthreads();
  for (int off = 1; off < 256; off <<= 1){
    int add = (t >= off) ? s[t - off] : 0;
    __syncthreads();
    s[t] += add;
    __syncthreads();
  }
  if (t < NBLK) bOff[t] = s[t] - v;        // exclusive
}

__global__ __launch_bounds__(256) void scanC_kernel(const int* __restrict__ counts,
    const int* __restrict__ bOff, int* __restrict__ row_start, int* __restrict__ cursor){
  __shared__ int s[256];
  const int t = threadIdx.x;
  const int idx = blockIdx.x*256 + t;
  const int c = (idx < NN) ? counts[idx] : 0;
  s[t] = c;
  __syncthreads();
  for (int off = 1; off < 256; off <<= 1){
    int add = (t >= off) ? s[t - off] : 0;
    __syncthreads();
    s[t] += add;
    __syncthreads();
  }
  const int excl = bOff[blockIdx.x] + s[t] - c;
  if (idx < NN){ row_start[idx] = excl; cursor[idx] = excl; }
  else if (idx == NN){ row_start[NN] = excl; }
}

// fill: also writes CSR-ordered src (srcS) so msg needs no eids->srcI indirection
__global__ void fill_kernel(const int* __restrict__ dstI, const int* __restrict__ srcI,
                            int* __restrict__ cursor, int* __restrict__ eids,
                            int* __restrict__ srcS){
  int e = blockIdx.x*256 + threadIdx.x;
  if (e < NE){
    int p = atomicAdd(&cursor[dstI[e]], 1);
    eids[p] = e;
    srcS[p] = srcI[e];
  }
}

// ---------------- GEMM: act(in @ W + bias) -> optional f32 out + optional bf16 out ----
// Safe in-place (outF == in): each block stages its own 32 input rows into LDS
// before writing, and writes only those rows.
__global__ __launch_bounds__(256) void gemm128(const float* __restrict__ in,
    const float* __restrict__ W, const float* __restrict__ bias,
    float* __restrict__ outF, ushort_t* __restrict__ outB, int n, int doRelu)
{
  __shared__ float Ws[HD*HD];
  __shared__ float Is[32*129];
  const int tid = threadIdx.x;
  const float4* W4 = (const float4*)W;
  float4* Ws4 = (float4*)Ws;
  #pragma unroll
  for (int i = 0; i < 16; ++i) Ws4[tid + i*256] = W4[tid + i*256];
  const int row0 = blockIdx.x * 32;
  #pragma unroll
  for (int i = 0; i < 4; ++i){
    int f = tid + i*256;
    int r = f >> 5, c4 = (f & 31) * 4;
    float4 v = make_float4(0.f,0.f,0.f,0.f);
    if (row0 + r < n) v = *(const float4*)(in + (size_t)(row0 + r)*HD + c4);
    float* dp = &Is[r*129 + c4];
    dp[0]=v.x; dp[1]=v.y; dp[2]=v.z; dp[3]=v.w;
  }
  __syncthreads();
  const int rg = tid >> 4;
  const int cg = tid & 15;
  float acc0[8] = {0,0,0,0,0,0,0,0};
  float acc1[8] = {0,0,0,0,0,0,0,0};
  #pragma unroll 4
  for (int k = 0; k < HD; ++k){
    float a0 = Is[rg*129 + k];
    float a1 = Is[(rg+16)*129 + k];
    #pragma unroll
    for (int j = 0; j < 8; ++j){
      float w = Ws[k*HD + cg + 16*j];
      acc0[j] = fmaf(a0, w, acc0[j]);
      acc1[j] = fmaf(a1, w, acc1[j]);
    }
  }
  const int r0 = row0 + rg, r1 = r0 + 16;
  #pragma unroll
  for (int j = 0; j < 8; ++j){
    int c = cg + 16*j;
    float b = bias ? bias[c] : 0.f;
    float x0 = acc0[j] + b, x1 = acc1[j] + b;
    if (doRelu){ x0 = fmaxf(x0, 0.f); x1 = fmaxf(x1, 0.f); }
    if (outF){
      if (r0 < n) outF[(size_t)r0*HD + c] = x0;
      if (r1 < n) outF[(size_t)r1*HD + c] = x1;
    }
    if (outB){
      if (r0 < n) outB[(size_t)r0*HD + c] = f2bf(x0);
      if (r1 < n) outB[(size_t)r1*HD + c] = f2bf(x1);
    }
  }
}

// ------------- fused mask+msg: h[v] += sum_e mask(U[s],V[v]) * hB[s] -------------
// One wave per dst node. Lane owns cols {2*lane, 2*lane+1}. V-slice loop-invariant.
// 4-edge unroll: 8 independent row-gathers in flight per wave.
__device__ __forceinline__ void edge_step(unsigned uu, unsigned hh,
    float vx, float vy, float w0, float w1, float b2,
    int eid, float* __restrict__ maskOut, int lane, float2& acc)
{
  float p = fmaxf(bflo(uu) + vx, 0.f) * w0;
  p = fmaf(fmaxf(bfhi(uu) + vy, 0.f), w1, p);
  #pragma unroll
  for (int m = 1; m < 64; m <<= 1) p += __shfl_xor(p, m, 64);
  float imp = sigmoidf_(p + b2);
  float mk  = sigmoidf_((imp - 0.4f) * 2.0f);
  if (maskOut != nullptr && lane == 0) maskOut[eid] = mk;
  acc.x = fmaf(mk, bflo(hh), acc.x);
  acc.y = fmaf(mk, bfhi(hh), acc.y);
}

__global__ __launch_bounds__(256) void mask_msg_kernel(
    float* __restrict__ h,                  // f32 h: read own row, write own row (in-place)
    const ushort_t* __restrict__ U, const ushort_t* __restrict__ V,
    const ushort_t* __restrict__ hB,
    const int* __restrict__ srcS, const int* __restrict__ eidS,
    const int* __restrict__ row_start,
    const float* __restrict__ Wm2, const float* __restrict__ bm2,
    float* __restrict__ maskOut)            // nullptr except final layer
{
  const int v = blockIdx.x*4 + (threadIdx.x >> 6);
  const int lane = threadIdx.x & 63;
  const float w0 = Wm2[2*lane], w1 = Wm2[2*lane+1];
  const float b2 = bm2[0];
  const unsigned vv = ((const unsigned*)(V + (size_t)v*HD))[lane];
  const float vx = bflo(vv), vy = bfhi(vv);
  float2 acc = ((const float2*)(h + (size_t)v*HD))[lane];
  const int beg = row_start[v], end = row_start[v+1];
  int idx = beg;
  for (; idx + 4 <= end; idx += 4){
    const int s0 = srcS[idx+0], s1 = srcS[idx+1], s2 = srcS[idx+2], s3 = srcS[idx+3];
    int e0=0,e1=0,e2=0,e3=0;
    if (maskOut){ e0=eidS[idx+0]; e1=eidS[idx+1]; e2=eidS[idx+2]; e3=eidS[idx+3]; }
    const unsigned uu0 = ((const unsigned*)(U  + (size_t)s0*HD))[lane];
    const unsigned hh0 = ((const unsigned*)(hB + (size_t)s0*HD))[lane];
    const unsigned uu1 = ((const unsigned*)(U  + (size_t)s1*HD))[lane];
    const unsigned hh1 = ((const unsigned*)(hB + (size_t)s1*HD))[lane];
    const unsigned uu2 = ((const unsigned*)(U  + (size_t)s2*HD))[lane];
    const unsigned hh2 = ((const unsigned*)(hB + (size_t)s2*HD))[lane];
    const unsigned uu3 = ((const unsigned*)(U  + (size_t)s3*HD))[lane];
    const unsigned hh3 = ((const unsigned*)(hB + (size_t)s3*HD))[lane];
    edge_step(uu0, hh0, vx, vy, w0, w1, b2, e0, maskOut, lane, acc);
    edge_step(uu1, hh1, vx, vy, w0, w1, b2, e1, maskOut, lane, acc);
    edge_step(uu2, hh2, vx, vy, w0, w1, b2, e2, maskOut, lane, acc);
    edge_step(uu3, hh3, vx, vy, w0, w1, b2, e3, maskOut, lane, acc);
  }
  for (; idx < end; ++idx){
    const int s = srcS[idx];
    const int e = maskOut ? eidS[idx] : 0;
    const unsigned uu = ((const unsigned*)(U  + (size_t)s*HD))[lane];
    const unsigned hh = ((const unsigned*)(hB + (size_t)s*HD))[lane];
    edge_step(uu, hh, vx, vy, w0, w1, b2, e, maskOut, lane, acc);
  }
  ((float2*)(h + (size_t)v*HD))[lane] = acc;
}

// ---------------- predictor ----------------
__global__ __launch_bounds__(128) void pred_kernel(const float* __restrict__ h,
  const float* __restrict__ Wp1, const float* __restrict__ bp1,
  const float* __restrict__ Wp2, const float* __restrict__ bp2,
  float* __restrict__ out0)
{
  __shared__ float red[128];
  const int t = threadIdx.x;
  float s = bp1[t];
  for (int k = 0; k < HD; ++k) s = fmaf(h[k], Wp1[k*HD + t], s);
  s = fmaxf(s, 0.f) * Wp2[t];
  red[t] = s;
  __syncthreads();
  for (int off = 64; off > 0; off >>= 1){
    if (t < off) red[t] += red[t + off];
    __syncthreads();
  }
  if (t == 0) out0[0] = red[0] + bp2[0];
}

extern "C" void kernel_launch(void* const* d_in, const int* in_sizes, int n_in,
                              void* d_out, int out_size, void* d_ws, size_t ws_size,
                              hipStream_t stream)
{
  (void)out_size;
  float* fOut = (float*)d_out;
  float* predOut = fOut;               // f32[0]
  float* maskOut = fOut + 1;           // f32[1 .. 1+NE)
  float* hOut    = fOut + 1 + NE;      // f32[1+NE ..)

  // ---- env tripwire (clean since R5; kept) ----
  static const int expSizes[14] = {6400000,1200000,16384,128,49152,384,32768,128,128,1,
                                   16384,128,128,1};
  const size_t NEEDED = 87100000;
  float diag = 0.f;
  if (n_in != 14) diag = 900.f + (float)n_in;
  else {
    for (int i = 0; i < 14; ++i)
      if (in_sizes[i] != expSizes[i]){ diag = 200.f + 16.f*(float)i; break; }
  }
  if (diag == 0.f && ws_size < NEEDED) diag = 5000.f + (float)(ws_size >> 20);

  if (diag != 0.f){
    write_scalar_kernel<<<1, 1, 0, stream>>>(predOut, diag);
    return;
  }

  const float* nf   = (const float*)d_in[0];
  const void*  ei   = d_in[1];
  const float* Wemb = (const float*)d_in[2];
  const float* bemb = (const float*)d_in[3];
  const float* Wgnn = (const float*)d_in[4];
  const float* bgnn = (const float*)d_in[5];
  const float* Wm1  = (const float*)d_in[6];
  const float* bm1  = (const float*)d_in[7];
  const float* Wm2  = (const float*)d_in[8];
  const float* bm2  = (const float*)d_in[9];
  const float* Wp1  = (const float*)d_in[10];
  const float* bp1  = (const float*)d_in[11];
  const float* Wp2  = (const float*)d_in[12];
  const float* bp2  = (const float*)d_in[13];

  float* hA    = (float*)d_ws;                        // h f32 (in-place msg+gemm) 25.6MB
  float* tmpU  = hA   + (size_t)NN*HD;                // Ub bf16 (lower half)      25.6MB
  float* Vbuf  = tmpU + (size_t)NN*HD;                // Vb bf16 + hB bf16         25.6MB
  float* srcSf = Vbuf + (size_t)NN*HD;                // srcS int (old maskF slot)  2.4MB
  int* srcS    = (int*)srcSf;                         // NE
  int* row_start = srcS + NE;                         // NN+1
  int* cursor  = row_start + (NN + 1);                // NN
  int* counts  = cursor + NN;                         // NN
  int* eids    = counts + NN;                         // NE
  int* srcW    = eids + NE;                           // NE
  int* dstW    = srcW + NE;                           // NE
  int* flag    = dstW + NE;                           // 1
  int* partial = flag + 1;                            // NBLK
  int* bOff    = partial + NBLK;                      // NBLK

  ushort_t* Ub = (ushort_t*)tmpU;                     // bf16 U
  ushort_t* Vb = (ushort_t*)Vbuf;                     // bf16 V
  ushort_t* hB = (ushort_t*)Vbuf + (size_t)NN*HD;     // bf16 h shadow

  // --- decode edge_index + dst histogram ---
  hipMemsetAsync(flag, 0, sizeof(int), stream);
  hipMemsetAsync(counts, 0, NN*sizeof(int), stream);
  detect_kernel<<<DET_SAMPLES/256, 256, 0, stream>>>((const unsigned int*)ei, flag);
  extract_kernel<<<(NE + 255)/256, 256, 0, stream>>>(ei, flag, srcW, dstW, counts);

  // --- CSR: hierarchical exclusive scan + fill (with CSR-ordered src) ---
  scanA_kernel<<<NBLK, 256, 0, stream>>>(counts, partial);
  scanB_kernel<<<1, 256, 0, stream>>>(partial, bOff);
  scanC_kernel<<<NBLK, 256, 0, stream>>>(counts, bOff, row_start, cursor);
  fill_kernel<<<(NE + 255)/256, 256, 0, stream>>>(dstW, srcW, cursor, eids, srcS);

  const int gGemm = (NN + 31)/32;
  // h = relu(nf@Wemb+bemb): f32 + bf16 shadow
  gemm128<<<gGemm, 256, 0, stream>>>(nf, Wemb, bemb, hA, hB, NN, 1);

  for (int L = 0; L < 3; ++L){
    float* hnext = (L < 2) ? hA : hOut;               // gemm in-place for L<2
    ushort_t* hBnext = (L < 2) ? hB : nullptr;
    float* mOut = (L < 2) ? nullptr : maskOut;
    gemm128<<<gGemm, 256, 0, stream>>>(hA, Wm1,         bm1,     nullptr, Ub, NN, 0);
    gemm128<<<gGemm, 256, 0, stream>>>(hA, Wm1 + HD*HD, nullptr, nullptr, Vb, NN, 0);
    mask_msg_kernel<<<NN/4, 256, 0, stream>>>(hA, Ub, Vb, hB, srcS, eids, row_start,
                                              Wm2, bm2, mOut);
    gemm128<<<gGemm, 256, 0, stream>>>(hA, Wgnn + (size_t)L*HD*HD, bgnn + (size_t)L*HD,
                                       hnext, hBnext, NN, 1);
  }

  pred_kernel<<<1, 128, 0, stream>>>(hOut, Wp1, bp1, Wp2, bp2, predOut);
}

// Round 14
// 607.346 us; speedup vs baseline: 1.9233x; 1.6116x over previous
//
#include <hip/hip_runtime.h>
#include <hip/hip_bf16.h>

#define NN 50000
#define NE 600000
#define HD 128
#define DET_SAMPLES 65536
#define NBLK 196                     // ceil((NN+1)/256)
#define GROWS 64                     // rows per GEMM block
#define GGRID ((NN + GROWS - 1)/GROWS)

typedef unsigned short ushort_t;

__device__ __forceinline__ float sigmoidf_(float x){ return 1.f/(1.f+__expf(-x)); }

__device__ __forceinline__ ushort_t f2bf(float f){
  unsigned int u = __float_as_uint(f);
  unsigned int r = (u + 0x7FFFu + ((u >> 16) & 1u)) >> 16;   // RNE
  return (ushort_t)r;
}

__device__ __forceinline__ float bflo(unsigned u){ return __uint_as_float(u << 16); }
__device__ __forceinline__ float bfhi(unsigned u){ return __uint_as_float(u & 0xFFFF0000u); }

// ---------------- diagnostic scalar write (env tripwire) ----------------
__global__ void write_scalar_kernel(float* __restrict__ p, float v){ p[0] = v; }

// ---------------- edge_index dtype detect + decode (+ dst histogram) ----------------
__global__ void detect_kernel(const unsigned int* __restrict__ w, int* __restrict__ flag){
  int i = blockIdx.x*256 + threadIdx.x;           // [0, DET_SAMPLES)
  int z = (w[2*i + 1] == 0u) ? 1 : 0;
  atomicAdd(flag, z);
}

__global__ void extract_kernel(const void* __restrict__ ei, const int* __restrict__ flag,
                               int* __restrict__ srcW, int* __restrict__ dstW,
                               int* __restrict__ counts){
  const int e = blockIdx.x*256 + threadIdx.x;
  if (e >= NE) return;
  int s, d;
  if (*flag > (DET_SAMPLES/2)){
    const long long* p = (const long long*)ei;
    s = (int)p[e]; d = (int)p[NE + e];
  } else {
    const int* p = (const int*)ei;
    s = p[e]; d = p[NE + e];
  }
  srcW[e] = s; dstW[e] = d;
  atomicAdd(&counts[d], 1);
}

// ---------------- hierarchical exclusive scan of counts[NN] ----------------
__global__ __launch_bounds__(256) void scanA_kernel(const int* __restrict__ counts,
                                                    int* __restrict__ partial){
  __shared__ int s[256];
  const int t = threadIdx.x;
  const int idx = blockIdx.x*256 + t;
  s[t] = (idx < NN) ? counts[idx] : 0;
  __syncthreads();
  for (int off = 128; off > 0; off >>= 1){
    if (t < off) s[t] += s[t + off];
    __syncthreads();
  }
  if (t == 0) partial[blockIdx.x] = s[0];
}

__global__ __launch_bounds__(256) void scanB_kernel(const int* __restrict__ partial,
                                                    int* __restrict__ bOff){
  __shared__ int s[256];
  const int t = threadIdx.x;
  const int v = (t < NBLK) ? partial[t] : 0;
  s[t] = v;
  __syncthreads();
  for (int off = 1; off < 256; off <<= 1){
    int add = (t >= off) ? s[t - off] : 0;
    __syncthreads();
    s[t] += add;
    __syncthreads();
  }
  if (t < NBLK) bOff[t] = s[t] - v;        // exclusive
}

__global__ __launch_bounds__(256) void scanC_kernel(const int* __restrict__ counts,
    const int* __restrict__ bOff, int* __restrict__ row_start, int* __restrict__ cursor){
  __shared__ int s[256];
  const int t = threadIdx.x;
  const int idx = blockIdx.x*256 + t;
  const int c = (idx < NN) ? counts[idx] : 0;
  s[t] = c;
  __syncthreads();
  for (int off = 1; off < 256; off <<= 1){
    int add = (t >= off) ? s[t - off] : 0;
    __syncthreads();
    s[t] += add;
    __syncthreads();
  }
  const int excl = bOff[blockIdx.x] + s[t] - c;
  if (idx < NN){ row_start[idx] = excl; cursor[idx] = excl; }
  else if (idx == NN){ row_start[NN] = excl; }
}

// fill: also writes CSR-ordered src (srcS) so msg needs no eids->srcI indirection
__global__ void fill_kernel(const int* __restrict__ dstI, const int* __restrict__ srcI,
                            int* __restrict__ cursor, int* __restrict__ eids,
                            int* __restrict__ srcS){
  int e = blockIdx.x*256 + threadIdx.x;
  if (e < NE){
    int p = atomicAdd(&cursor[dstI[e]], 1);
    eids[p] = e;
    srcS[p] = srcI[e];
  }
}

// ---------------- GEMM (single W): out = act(in @ W + bias) ----------------
// W read from L2 (coalesced float4 per k); LDS holds only the 64-row input tile.
// Safe in-place (outF == in): block stages its rows before writing, writes only them.
__global__ __launch_bounds__(256) void gemm_h(const float* __restrict__ in,
    const float* __restrict__ W, const float* __restrict__ bias,
    float* __restrict__ outF, ushort_t* __restrict__ outB, int n, int doRelu)
{
  __shared__ float Is[GROWS*HD];                 // 32 KB
  const int t = threadIdx.x;
  const int row0 = blockIdx.x * GROWS;
  const float4* src = (const float4*)(in + (size_t)row0*HD);
  float4* dst4 = (float4*)Is;
  #pragma unroll
  for (int i = 0; i < 8; ++i){
    int idx = t + i*256;                         // 2048 float4
    float4 v = make_float4(0.f,0.f,0.f,0.f);
    if (row0 + (idx >> 5) < n) v = src[idx];
    dst4[idx] = v;
  }
  __syncthreads();
  const int c4 = t & 31;                         // float4 column
  const int rg = t >> 5;                         // 0..7; rows m*8+rg
  float4 acc[8];
  #pragma unroll
  for (int m = 0; m < 8; ++m) acc[m] = make_float4(0.f,0.f,0.f,0.f);
  #pragma unroll 4
  for (int k = 0; k < HD; ++k){
    const float4 w = ((const float4*)(W + (size_t)k*HD))[c4];
    #pragma unroll
    for (int m = 0; m < 8; ++m){
      const float a = Is[(m*8+rg)*HD + k];       // broadcast read
      acc[m].x = fmaf(a, w.x, acc[m].x);
      acc[m].y = fmaf(a, w.y, acc[m].y);
      acc[m].z = fmaf(a, w.z, acc[m].z);
      acc[m].w = fmaf(a, w.w, acc[m].w);
    }
  }
  float4 b = make_float4(0.f,0.f,0.f,0.f);
  if (bias) b = ((const float4*)bias)[c4];
  #pragma unroll
  for (int m = 0; m < 8; ++m){
    const int r = row0 + m*8 + rg;
    if (r >= n) continue;
    float4 x = acc[m];
    x.x += b.x; x.y += b.y; x.z += b.z; x.w += b.w;
    if (doRelu){
      x.x = fmaxf(x.x, 0.f); x.y = fmaxf(x.y, 0.f);
      x.z = fmaxf(x.z, 0.f); x.w = fmaxf(x.w, 0.f);
    }
    if (outF) ((float4*)(outF + (size_t)r*HD))[c4] = x;
    if (outB){
      ushort4 p;
      p.x = f2bf(x.x); p.y = f2bf(x.y); p.z = f2bf(x.z); p.w = f2bf(x.w);
      ((ushort4*)(outB + (size_t)r*HD))[c4] = p;
    }
  }
}

// ---------------- fused U/V GEMM: U = in@Wu + bu, V = in@Wv (both bf16 out) ----------
__global__ __launch_bounds__(256) void gemm_uv(const float* __restrict__ in,
    const float* __restrict__ Wu, const float* __restrict__ Wv,
    const float* __restrict__ biasU,
    ushort_t* __restrict__ outU, ushort_t* __restrict__ outV, int n)
{
  __shared__ float Is[GROWS*HD];                 // 32 KB
  const int t = threadIdx.x;
  const int row0 = blockIdx.x * GROWS;
  const float4* src = (const float4*)(in + (size_t)row0*HD);
  float4* dst4 = (float4*)Is;
  #pragma unroll
  for (int i = 0; i < 8; ++i){
    int idx = t + i*256;
    float4 v = make_float4(0.f,0.f,0.f,0.f);
    if (row0 + (idx >> 5) < n) v = src[idx];
    dst4[idx] = v;
  }
  __syncthreads();
  const int c4 = t & 31;
  const int rg = t >> 5;
  float4 aU[8], aV[8];
  #pragma unroll
  for (int m = 0; m < 8; ++m){
    aU[m] = make_float4(0.f,0.f,0.f,0.f);
    aV[m] = make_float4(0.f,0.f,0.f,0.f);
  }
  #pragma unroll 2
  for (int k = 0; k < HD; ++k){
    const float4 wu = ((const float4*)(Wu + (size_t)k*HD))[c4];
    const float4 wv = ((const float4*)(Wv + (size_t)k*HD))[c4];
    #pragma unroll
    for (int m = 0; m < 8; ++m){
      const float a = Is[(m*8+rg)*HD + k];
      aU[m].x = fmaf(a, wu.x, aU[m].x);
      aU[m].y = fmaf(a, wu.y, aU[m].y);
      aU[m].z = fmaf(a, wu.z, aU[m].z);
      aU[m].w = fmaf(a, wu.w, aU[m].w);
      aV[m].x = fmaf(a, wv.x, aV[m].x);
      aV[m].y = fmaf(a, wv.y, aV[m].y);
      aV[m].z = fmaf(a, wv.z, aV[m].z);
      aV[m].w = fmaf(a, wv.w, aV[m].w);
    }
  }
  const float4 b = ((const float4*)biasU)[c4];
  #pragma unroll
  for (int m = 0; m < 8; ++m){
    const int r = row0 + m*8 + rg;
    if (r >= n) continue;
    float4 xu = aU[m];
    xu.x += b.x; xu.y += b.y; xu.z += b.z; xu.w += b.w;
    ushort4 pu;
    pu.x = f2bf(xu.x); pu.y = f2bf(xu.y); pu.z = f2bf(xu.z); pu.w = f2bf(xu.w);
    ((ushort4*)(outU + (size_t)r*HD))[c4] = pu;
    ushort4 pv;
    pv.x = f2bf(aV[m].x); pv.y = f2bf(aV[m].y); pv.z = f2bf(aV[m].z); pv.w = f2bf(aV[m].w);
    ((ushort4*)(outV + (size_t)r*HD))[c4] = pv;
  }
}

// ------------- fused mask+msg: h[v] += sum_e mask(U[s],V[v]) * hB[s] -------------
__device__ __forceinline__ void edge_step(unsigned uu, unsigned hh,
    float vx, float vy, float w0, float w1, float b2,
    int eid, float* __restrict__ maskOut, int lane, float2& acc)
{
  float p = fmaxf(bflo(uu) + vx, 0.f) * w0;
  p = fmaf(fmaxf(bfhi(uu) + vy, 0.f), w1, p);
  #pragma unroll
  for (int m = 1; m < 64; m <<= 1) p += __shfl_xor(p, m, 64);
  float imp = sigmoidf_(p + b2);
  float mk  = sigmoidf_((imp - 0.4f) * 2.0f);
  if (maskOut != nullptr && lane == 0) maskOut[eid] = mk;
  acc.x = fmaf(mk, bflo(hh), acc.x);
  acc.y = fmaf(mk, bfhi(hh), acc.y);
}

__global__ __launch_bounds__(256) void mask_msg_kernel(
    float* __restrict__ h,                  // in-place: read own row, write own row
    const ushort_t* __restrict__ U, const ushort_t* __restrict__ V,
    const ushort_t* __restrict__ hB,
    const int* __restrict__ srcS, const int* __restrict__ eidS,
    const int* __restrict__ row_start,
    const float* __restrict__ Wm2, const float* __restrict__ bm2,
    float* __restrict__ maskOut)            // nullptr except final layer
{
  const int v = blockIdx.x*4 + (threadIdx.x >> 6);
  const int lane = threadIdx.x & 63;
  const float w0 = Wm2[2*lane], w1 = Wm2[2*lane+1];
  const float b2 = bm2[0];
  const unsigned vv = ((const unsigned*)(V + (size_t)v*HD))[lane];
  const float vx = bflo(vv), vy = bfhi(vv);
  float2 acc = ((const float2*)(h + (size_t)v*HD))[lane];
  const int beg = row_start[v], end = row_start[v+1];
  int idx = beg;
  for (; idx + 4 <= end; idx += 4){
    const int s0 = srcS[idx+0], s1 = srcS[idx+1], s2 = srcS[idx+2], s3 = srcS[idx+3];
    int e0=0,e1=0,e2=0,e3=0;
    if (maskOut){ e0=eidS[idx+0]; e1=eidS[idx+1]; e2=eidS[idx+2]; e3=eidS[idx+3]; }
    const unsigned uu0 = ((const unsigned*)(U  + (size_t)s0*HD))[lane];
    const unsigned hh0 = ((const unsigned*)(hB + (size_t)s0*HD))[lane];
    const unsigned uu1 = ((const unsigned*)(U  + (size_t)s1*HD))[lane];
    const unsigned hh1 = ((const unsigned*)(hB + (size_t)s1*HD))[lane];
    const unsigned uu2 = ((const unsigned*)(U  + (size_t)s2*HD))[lane];
    const unsigned hh2 = ((const unsigned*)(hB + (size_t)s2*HD))[lane];
    const unsigned uu3 = ((const unsigned*)(U  + (size_t)s3*HD))[lane];
    const unsigned hh3 = ((const unsigned*)(hB + (size_t)s3*HD))[lane];
    edge_step(uu0, hh0, vx, vy, w0, w1, b2, e0, maskOut, lane, acc);
    edge_step(uu1, hh1, vx, vy, w0, w1, b2, e1, maskOut, lane, acc);
    edge_step(uu2, hh2, vx, vy, w0, w1, b2, e2, maskOut, lane, acc);
    edge_step(uu3, hh3, vx, vy, w0, w1, b2, e3, maskOut, lane, acc);
  }
  for (; idx < end; ++idx){
    const int s = srcS[idx];
    const int e = maskOut ? eidS[idx] : 0;
    const unsigned uu = ((const unsigned*)(U  + (size_t)s*HD))[lane];
    const unsigned hh = ((const unsigned*)(hB + (size_t)s*HD))[lane];
    edge_step(uu, hh, vx, vy, w0, w1, b2, e, maskOut, lane, acc);
  }
  ((float2*)(h + (size_t)v*HD))[lane] = acc;
}

// ---------------- predictor ----------------
__global__ __launch_bounds__(128) void pred_kernel(const float* __restrict__ h,
  const float* __restrict__ Wp1, const float* __restrict__ bp1,
  const float* __restrict__ Wp2, const float* __restrict__ bp2,
  float* __restrict__ out0)
{
  __shared__ float red[128];
  const int t = threadIdx.x;
  float s = bp1[t];
  for (int k = 0; k < HD; ++k) s = fmaf(h[k], Wp1[k*HD + t], s);
  s = fmaxf(s, 0.f) * Wp2[t];
  red[t] = s;
  __syncthreads();
  for (int off = 64; off > 0; off >>= 1){
    if (t < off) red[t] += red[t + off];
    __syncthreads();
  }
  if (t == 0) out0[0] = red[0] + bp2[0];
}

extern "C" void kernel_launch(void* const* d_in, const int* in_sizes, int n_in,
                              void* d_out, int out_size, void* d_ws, size_t ws_size,
                              hipStream_t stream)
{
  (void)out_size;
  float* fOut = (float*)d_out;
  float* predOut = fOut;               // f32[0]
  float* maskOut = fOut + 1;           // f32[1 .. 1+NE)
  float* hOut    = fOut + 1 + NE;      // f32[1+NE ..)

  // ---- env tripwire (clean since R5; kept) ----
  static const int expSizes[14] = {6400000,1200000,16384,128,49152,384,32768,128,128,1,
                                   16384,128,128,1};
  const size_t NEEDED = 87100000;
  float diag = 0.f;
  if (n_in != 14) diag = 900.f + (float)n_in;
  else {
    for (int i = 0; i < 14; ++i)
      if (in_sizes[i] != expSizes[i]){ diag = 200.f + 16.f*(float)i; break; }
  }
  if (diag == 0.f && ws_size < NEEDED) diag = 5000.f + (float)(ws_size >> 20);

  if (diag != 0.f){
    write_scalar_kernel<<<1, 1, 0, stream>>>(predOut, diag);
    return;
  }

  const float* nf   = (const float*)d_in[0];
  const void*  ei   = d_in[1];
  const float* Wemb = (const float*)d_in[2];
  const float* bemb = (const float*)d_in[3];
  const float* Wgnn = (const float*)d_in[4];
  const float* bgnn = (const float*)d_in[5];
  const float* Wm1  = (const float*)d_in[6];
  const float* bm1  = (const float*)d_in[7];
  const float* Wm2  = (const float*)d_in[8];
  const float* bm2  = (const float*)d_in[9];
  const float* Wp1  = (const float*)d_in[10];
  const float* bp1  = (const float*)d_in[11];
  const float* Wp2  = (const float*)d_in[12];
  const float* bp2  = (const float*)d_in[13];

  float* hA    = (float*)d_ws;                        // h f32 (in-place)          25.6MB
  float* tmpU  = hA   + (size_t)NN*HD;                // Ub bf16                   25.6MB
  float* Vbuf  = tmpU + (size_t)NN*HD;                // Vb bf16 + hB bf16         25.6MB
  float* srcSf = Vbuf + (size_t)NN*HD;                // srcS int                   2.4MB
  int* srcS    = (int*)srcSf;                         // NE
  int* row_start = srcS + NE;                         // NN+1
  int* cursor  = row_start + (NN + 1);                // NN
  int* counts  = cursor + NN;                         // NN
  int* eids    = counts + NN;                         // NE
  int* srcW    = eids + NE;                           // NE
  int* dstW    = srcW + NE;                           // NE
  int* flag    = dstW + NE;                           // 1
  int* partial = flag + 1;                            // NBLK
  int* bOff    = partial + NBLK;                      // NBLK

  ushort_t* Ub = (ushort_t*)tmpU;                     // bf16 U
  ushort_t* Vb = (ushort_t*)Vbuf;                     // bf16 V
  ushort_t* hB = (ushort_t*)Vbuf + (size_t)NN*HD;     // bf16 h shadow

  // --- decode edge_index + dst histogram ---
  hipMemsetAsync(flag, 0, sizeof(int), stream);
  hipMemsetAsync(counts, 0, NN*sizeof(int), stream);
  detect_kernel<<<DET_SAMPLES/256, 256, 0, stream>>>((const unsigned int*)ei, flag);
  extract_kernel<<<(NE + 255)/256, 256, 0, stream>>>(ei, flag, srcW, dstW, counts);

  // --- CSR: hierarchical exclusive scan + fill (with CSR-ordered src) ---
  scanA_kernel<<<NBLK, 256, 0, stream>>>(counts, partial);
  scanB_kernel<<<1, 256, 0, stream>>>(partial, bOff);
  scanC_kernel<<<NBLK, 256, 0, stream>>>(counts, bOff, row_start, cursor);
  fill_kernel<<<(NE + 255)/256, 256, 0, stream>>>(dstW, srcW, cursor, eids, srcS);

  // h = relu(nf@Wemb+bemb): f32 + bf16 shadow
  gemm_h<<<GGRID, 256, 0, stream>>>(nf, Wemb, bemb, hA, hB, NN, 1);

  for (int L = 0; L < 3; ++L){
    float* hnext = (L < 2) ? hA : hOut;               // h-gemm in-place for L<2
    ushort_t* hBnext = (L < 2) ? hB : nullptr;
    float* mOut = (L < 2) ? nullptr : maskOut;
    gemm_uv<<<GGRID, 256, 0, stream>>>(hA, Wm1, Wm1 + HD*HD, bm1, Ub, Vb, NN);
    mask_msg_kernel<<<NN/4, 256, 0, stream>>>(hA, Ub, Vb, hB, srcS, eids, row_start,
                                              Wm2, bm2, mOut);
    gemm_h<<<GGRID, 256, 0, stream>>>(hA, Wgnn + (size_t)L*HD*HD, bgnn + (size_t)L*HD,
                                      hnext, hBnext, NN, 1);
  }

  pred_kernel<<<1, 128, 0, stream>>>(hOut, Wp1, bp1, Wp2, bp2, predOut);
}

// Round 15
// 554.070 us; speedup vs baseline: 2.1082x; 1.0962x over previous
//
#include <hip/hip_runtime.h>
#include <hip/hip_bf16.h>

#define NN 50000
#define NE 600000
#define HD 128
#define DET_SAMPLES 65536
#define NBLK 196                     // ceil((NN+1)/256)
#define GROWS 64                     // rows per GEMM block
#define GGRID ((NN + GROWS - 1)/GROWS)

typedef unsigned short ushort_t;

__device__ __forceinline__ float sigmoidf_(float x){ return 1.f/(1.f+__expf(-x)); }

__device__ __forceinline__ ushort_t f2bf(float f){
  unsigned int u = __float_as_uint(f);
  unsigned int r = (u + 0x7FFFu + ((u >> 16) & 1u)) >> 16;   // RNE
  return (ushort_t)r;
}

__device__ __forceinline__ float bflo(unsigned u){ return __uint_as_float(u << 16); }
__device__ __forceinline__ float bfhi(unsigned u){ return __uint_as_float(u & 0xFFFF0000u); }

// ---------------- diagnostic scalar write (env tripwire) ----------------
__global__ void write_scalar_kernel(float* __restrict__ p, float v){ p[0] = v; }

// ---------------- edge_index dtype detect + decode (+ dst histogram) ----------------
__global__ void detect_kernel(const unsigned int* __restrict__ w, int* __restrict__ flag){
  int i = blockIdx.x*256 + threadIdx.x;           // [0, DET_SAMPLES)
  int z = (w[2*i + 1] == 0u) ? 1 : 0;
  atomicAdd(flag, z);
}

__global__ void extract_kernel(const void* __restrict__ ei, const int* __restrict__ flag,
                               int* __restrict__ srcW, int* __restrict__ dstW,
                               int* __restrict__ counts){
  const int e = blockIdx.x*256 + threadIdx.x;
  if (e >= NE) return;
  int s, d;
  if (*flag > (DET_SAMPLES/2)){
    const long long* p = (const long long*)ei;
    s = (int)p[e]; d = (int)p[NE + e];
  } else {
    const int* p = (const int*)ei;
    s = p[e]; d = p[NE + e];
  }
  srcW[e] = s; dstW[e] = d;
  atomicAdd(&counts[d], 1);
}

// ---------------- hierarchical exclusive scan of counts[NN] ----------------
__global__ __launch_bounds__(256) void scanA_kernel(const int* __restrict__ counts,
                                                    int* __restrict__ partial){
  __shared__ int s[256];
  const int t = threadIdx.x;
  const int idx = blockIdx.x*256 + t;
  s[t] = (idx < NN) ? counts[idx] : 0;
  __syncthreads();
  for (int off = 128; off > 0; off >>= 1){
    if (t < off) s[t] += s[t + off];
    __syncthreads();
  }
  if (t == 0) partial[blockIdx.x] = s[0];
}

__global__ __launch_bounds__(256) void scanB_kernel(const int* __restrict__ partial,
                                                    int* __restrict__ bOff){
  __shared__ int s[256];
  const int t = threadIdx.x;
  const int v = (t < NBLK) ? partial[t] : 0;
  s[t] = v;
  __syncthreads();
  for (int off = 1; off < 256; off <<= 1){
    int add = (t >= off) ? s[t - off] : 0;
    __syncthreads();
    s[t] += add;
    __syncthreads();
  }
  if (t < NBLK) bOff[t] = s[t] - v;        // exclusive
}

__global__ __launch_bounds__(256) void scanC_kernel(const int* __restrict__ counts,
    const int* __restrict__ bOff, int* __restrict__ row_start, int* __restrict__ cursor){
  __shared__ int s[256];
  const int t = threadIdx.x;
  const int idx = blockIdx.x*256 + t;
  const int c = (idx < NN) ? counts[idx] : 0;
  s[t] = c;
  __syncthreads();
  for (int off = 1; off < 256; off <<= 1){
    int add = (t >= off) ? s[t - off] : 0;
    __syncthreads();
    s[t] += add;
    __syncthreads();
  }
  const int excl = bOff[blockIdx.x] + s[t] - c;
  if (idx < NN){ row_start[idx] = excl; cursor[idx] = excl; }
  else if (idx == NN){ row_start[NN] = excl; }
}

// fill: also writes CSR-ordered src (srcS) so msg needs no eids->srcI indirection
__global__ void fill_kernel(const int* __restrict__ dstI, const int* __restrict__ srcI,
                            int* __restrict__ cursor, int* __restrict__ eids,
                            int* __restrict__ srcS){
  int e = blockIdx.x*256 + threadIdx.x;
  if (e < NE){
    int p = atomicAdd(&cursor[dstI[e]], 1);
    eids[p] = e;
    srcS[p] = srcI[e];
  }
}

// ---------------- GEMM (single W): out = act(in @ W + bias) ----------------
// W read from L2 (coalesced float4 per k); LDS holds only the 64-row input tile.
// Safe in-place (outF == in): block stages its rows before writing, writes only them.
__global__ __launch_bounds__(256) void gemm_h(const float* __restrict__ in,
    const float* __restrict__ W, const float* __restrict__ bias,
    float* __restrict__ outF, ushort_t* __restrict__ outB, int n, int doRelu)
{
  __shared__ float Is[GROWS*HD];                 // 32 KB
  const int t = threadIdx.x;
  const int row0 = blockIdx.x * GROWS;
  const float4* src = (const float4*)(in + (size_t)row0*HD);
  float4* dst4 = (float4*)Is;
  #pragma unroll
  for (int i = 0; i < 8; ++i){
    int idx = t + i*256;                         // 2048 float4
    float4 v = make_float4(0.f,0.f,0.f,0.f);
    if (row0 + (idx >> 5) < n) v = src[idx];
    dst4[idx] = v;
  }
  __syncthreads();
  const int c4 = t & 31;                         // float4 column
  const int rg = t >> 5;                         // 0..7; rows m*8+rg
  float4 acc[8];
  #pragma unroll
  for (int m = 0; m < 8; ++m) acc[m] = make_float4(0.f,0.f,0.f,0.f);
  #pragma unroll 4
  for (int k = 0; k < HD; ++k){
    const float4 w = ((const float4*)(W + (size_t)k*HD))[c4];
    #pragma unroll
    for (int m = 0; m < 8; ++m){
      const float a = Is[(m*8+rg)*HD + k];       // broadcast read
      acc[m].x = fmaf(a, w.x, acc[m].x);
      acc[m].y = fmaf(a, w.y, acc[m].y);
      acc[m].z = fmaf(a, w.z, acc[m].z);
      acc[m].w = fmaf(a, w.w, acc[m].w);
    }
  }
  float4 b = make_float4(0.f,0.f,0.f,0.f);
  if (bias) b = ((const float4*)bias)[c4];
  #pragma unroll
  for (int m = 0; m < 8; ++m){
    const int r = row0 + m*8 + rg;
    if (r >= n) continue;
    float4 x = acc[m];
    x.x += b.x; x.y += b.y; x.z += b.z; x.w += b.w;
    if (doRelu){
      x.x = fmaxf(x.x, 0.f); x.y = fmaxf(x.y, 0.f);
      x.z = fmaxf(x.z, 0.f); x.w = fmaxf(x.w, 0.f);
    }
    if (outF) ((float4*)(outF + (size_t)r*HD))[c4] = x;
    if (outB){
      ushort4 p;
      p.x = f2bf(x.x); p.y = f2bf(x.y); p.z = f2bf(x.z); p.w = f2bf(x.w);
      ((ushort4*)(outB + (size_t)r*HD))[c4] = p;
    }
  }
}

// ---------------- fused U/V GEMM: U = in@Wu + bu, V = in@Wv (both bf16 out) ----------
__global__ __launch_bounds__(256) void gemm_uv(const float* __restrict__ in,
    const float* __restrict__ Wu, const float* __restrict__ Wv,
    const float* __restrict__ biasU,
    ushort_t* __restrict__ outU, ushort_t* __restrict__ outV, int n)
{
  __shared__ float Is[GROWS*HD];                 // 32 KB
  const int t = threadIdx.x;
  const int row0 = blockIdx.x * GROWS;
  const float4* src = (const float4*)(in + (size_t)row0*HD);
  float4* dst4 = (float4*)Is;
  #pragma unroll
  for (int i = 0; i < 8; ++i){
    int idx = t + i*256;
    float4 v = make_float4(0.f,0.f,0.f,0.f);
    if (row0 + (idx >> 5) < n) v = src[idx];
    dst4[idx] = v;
  }
  __syncthreads();
  const int c4 = t & 31;
  const int rg = t >> 5;
  float4 aU[8], aV[8];
  #pragma unroll
  for (int m = 0; m < 8; ++m){
    aU[m] = make_float4(0.f,0.f,0.f,0.f);
    aV[m] = make_float4(0.f,0.f,0.f,0.f);
  }
  #pragma unroll 2
  for (int k = 0; k < HD; ++k){
    const float4 wu = ((const float4*)(Wu + (size_t)k*HD))[c4];
    const float4 wv = ((const float4*)(Wv + (size_t)k*HD))[c4];
    #pragma unroll
    for (int m = 0; m < 8; ++m){
      const float a = Is[(m*8+rg)*HD + k];
      aU[m].x = fmaf(a, wu.x, aU[m].x);
      aU[m].y = fmaf(a, wu.y, aU[m].y);
      aU[m].z = fmaf(a, wu.z, aU[m].z);
      aU[m].w = fmaf(a, wu.w, aU[m].w);
      aV[m].x = fmaf(a, wv.x, aV[m].x);
      aV[m].y = fmaf(a, wv.y, aV[m].y);
      aV[m].z = fmaf(a, wv.z, aV[m].z);
      aV[m].w = fmaf(a, wv.w, aV[m].w);
    }
  }
  const float4 b = ((const float4*)biasU)[c4];
  #pragma unroll
  for (int m = 0; m < 8; ++m){
    const int r = row0 + m*8 + rg;
    if (r >= n) continue;
    float4 xu = aU[m];
    xu.x += b.x; xu.y += b.y; xu.z += b.z; xu.w += b.w;
    ushort4 pu;
    pu.x = f2bf(xu.x); pu.y = f2bf(xu.y); pu.z = f2bf(xu.z); pu.w = f2bf(xu.w);
    ((ushort4*)(outU + (size_t)r*HD))[c4] = pu;
    ushort4 pv;
    pv.x = f2bf(aV[m].x); pv.y = f2bf(aV[m].y); pv.z = f2bf(aV[m].z); pv.w = f2bf(aV[m].w);
    ((ushort4*)(outV + (size_t)r*HD))[c4] = pv;
  }
}

// ------------- fused mask+msg, 16-lane edge groups -------------
// One wave per dst node; 4 groups of 16 lanes each take every 4th edge.
// Lane sub owns cols sub*8..sub*8+7 (uint4 of bf16). Group-local 4-step reduce;
// one cross-group combine per node.
__global__ __launch_bounds__(256) void mask_msg_kernel(
    float* __restrict__ h,                  // in-place: read own row, write own row
    const ushort_t* __restrict__ U, const ushort_t* __restrict__ V,
    const ushort_t* __restrict__ hB,
    const int* __restrict__ srcS, const int* __restrict__ eidS,
    const int* __restrict__ row_start,
    const float* __restrict__ Wm2, const float* __restrict__ bm2,
    float* __restrict__ maskOut)            // nullptr except final layer
{
  const int v = blockIdx.x*4 + (threadIdx.x >> 6);
  const int lane = threadIdx.x & 63;
  const int g   = lane >> 4;                // edge group 0..3
  const int sub = lane & 15;                // lane in group
  const float4 wA = ((const float4*)Wm2)[sub*2];      // cols sub*8..+3
  const float4 wB = ((const float4*)Wm2)[sub*2+1];    // cols sub*8+4..+7
  const float b2 = bm2[0];
  const uint4 vv = ((const uint4*)(V + (size_t)v*HD))[sub];
  float a0=0.f,a1=0.f,a2=0.f,a3=0.f,a4=0.f,a5=0.f,a6=0.f,a7=0.f;
  const int beg = row_start[v], end = row_start[v+1];
  for (int idx = beg + g; idx < end; idx += 4){
    const int s = srcS[idx];
    const uint4 uu = ((const uint4*)(U  + (size_t)s*HD))[sub];
    const uint4 hh = ((const uint4*)(hB + (size_t)s*HD))[sub];
    float p;
    p = fmaxf(bflo(uu.x)+bflo(vv.x), 0.f) * wA.x;
    p = fmaf(fmaxf(bfhi(uu.x)+bfhi(vv.x), 0.f), wA.y, p);
    p = fmaf(fmaxf(bflo(uu.y)+bflo(vv.y), 0.f), wA.z, p);
    p = fmaf(fmaxf(bfhi(uu.y)+bfhi(vv.y), 0.f), wA.w, p);
    p = fmaf(fmaxf(bflo(uu.z)+bflo(vv.z), 0.f), wB.x, p);
    p = fmaf(fmaxf(bfhi(uu.z)+bfhi(vv.z), 0.f), wB.y, p);
    p = fmaf(fmaxf(bflo(uu.w)+bflo(vv.w), 0.f), wB.z, p);
    p = fmaf(fmaxf(bfhi(uu.w)+bfhi(vv.w), 0.f), wB.w, p);
    p += __shfl_xor(p, 1, 64);
    p += __shfl_xor(p, 2, 64);
    p += __shfl_xor(p, 4, 64);
    p += __shfl_xor(p, 8, 64);
    const float imp = sigmoidf_(p + b2);
    const float mk  = sigmoidf_((imp - 0.4f) * 2.0f);
    if (maskOut != nullptr && sub == 0) maskOut[eidS[idx]] = mk;
    a0 = fmaf(mk, bflo(hh.x), a0);
    a1 = fmaf(mk, bfhi(hh.x), a1);
    a2 = fmaf(mk, bflo(hh.y), a2);
    a3 = fmaf(mk, bfhi(hh.y), a3);
    a4 = fmaf(mk, bflo(hh.z), a4);
    a5 = fmaf(mk, bfhi(hh.z), a5);
    a6 = fmaf(mk, bflo(hh.w), a6);
    a7 = fmaf(mk, bfhi(hh.w), a7);
  }
  // cross-group combine (sum over the 4 groups)
  a0 += __shfl_xor(a0, 16, 64); a0 += __shfl_xor(a0, 32, 64);
  a1 += __shfl_xor(a1, 16, 64); a1 += __shfl_xor(a1, 32, 64);
  a2 += __shfl_xor(a2, 16, 64); a2 += __shfl_xor(a2, 32, 64);
  a3 += __shfl_xor(a3, 16, 64); a3 += __shfl_xor(a3, 32, 64);
  a4 += __shfl_xor(a4, 16, 64); a4 += __shfl_xor(a4, 32, 64);
  a5 += __shfl_xor(a5, 16, 64); a5 += __shfl_xor(a5, 32, 64);
  a6 += __shfl_xor(a6, 16, 64); a6 += __shfl_xor(a6, 32, 64);
  a7 += __shfl_xor(a7, 16, 64); a7 += __shfl_xor(a7, 32, 64);
  if (g == 0){
    float4* hrow = (float4*)(h + (size_t)v*HD);
    float4 x0 = hrow[sub*2];
    float4 x1 = hrow[sub*2+1];
    x0.x += a0; x0.y += a1; x0.z += a2; x0.w += a3;
    x1.x += a4; x1.y += a5; x1.z += a6; x1.w += a7;
    hrow[sub*2]   = x0;
    hrow[sub*2+1] = x1;
  }
}

// ---------------- predictor ----------------
__global__ __launch_bounds__(128) void pred_kernel(const float* __restrict__ h,
  const float* __restrict__ Wp1, const float* __restrict__ bp1,
  const float* __restrict__ Wp2, const float* __restrict__ bp2,
  float* __restrict__ out0)
{
  __shared__ float red[128];
  const int t = threadIdx.x;
  float s = bp1[t];
  for (int k = 0; k < HD; ++k) s = fmaf(h[k], Wp1[k*HD + t], s);
  s = fmaxf(s, 0.f) * Wp2[t];
  red[t] = s;
  __syncthreads();
  for (int off = 64; off > 0; off >>= 1){
    if (t < off) red[t] += red[t + off];
    __syncthreads();
  }
  if (t == 0) out0[0] = red[0] + bp2[0];
}

extern "C" void kernel_launch(void* const* d_in, const int* in_sizes, int n_in,
                              void* d_out, int out_size, void* d_ws, size_t ws_size,
                              hipStream_t stream)
{
  (void)out_size;
  float* fOut = (float*)d_out;
  float* predOut = fOut;               // f32[0]
  float* maskOut = fOut + 1;           // f32[1 .. 1+NE)
  float* hOut    = fOut + 1 + NE;      // f32[1+NE ..)

  // ---- env tripwire (clean since R5; kept) ----
  static const int expSizes[14] = {6400000,1200000,16384,128,49152,384,32768,128,128,1,
                                   16384,128,128,1};
  const size_t NEEDED = 87100000;
  float diag = 0.f;
  if (n_in != 14) diag = 900.f + (float)n_in;
  else {
    for (int i = 0; i < 14; ++i)
      if (in_sizes[i] != expSizes[i]){ diag = 200.f + 16.f*(float)i; break; }
  }
  if (diag == 0.f && ws_size < NEEDED) diag = 5000.f + (float)(ws_size >> 20);

  if (diag != 0.f){
    write_scalar_kernel<<<1, 1, 0, stream>>>(predOut, diag);
    return;
  }

  const float* nf   = (const float*)d_in[0];
  const void*  ei   = d_in[1];
  const float* Wemb = (const float*)d_in[2];
  const float* bemb = (const float*)d_in[3];
  const float* Wgnn = (const float*)d_in[4];
  const float* bgnn = (const float*)d_in[5];
  const float* Wm1  = (const float*)d_in[6];
  const float* bm1  = (const float*)d_in[7];
  const float* Wm2  = (const float*)d_in[8];
  const float* bm2  = (const float*)d_in[9];
  const float* Wp1  = (const float*)d_in[10];
  const float* bp1  = (const float*)d_in[11];
  const float* Wp2  = (const float*)d_in[12];
  const float* bp2  = (const float*)d_in[13];

  float* hA    = (float*)d_ws;                        // h f32 (in-place)          25.6MB
  float* tmpU  = hA   + (size_t)NN*HD;                // Ub bf16                   25.6MB
  float* Vbuf  = tmpU + (size_t)NN*HD;                // Vb bf16 + hB bf16         25.6MB
  float* srcSf = Vbuf + (size_t)NN*HD;                // srcS int                   2.4MB
  int* srcS    = (int*)srcSf;                         // NE
  int* row_start = srcS + NE;                         // NN+1
  int* cursor  = row_start + (NN + 1);                // NN
  int* counts  = cursor + NN;                         // NN
  int* eids    = counts + NN;                         // NE
  int* srcW    = eids + NE;                           // NE
  int* dstW    = srcW + NE;                           // NE
  int* flag    = dstW + NE;                           // 1
  int* partial = flag + 1;                            // NBLK
  int* bOff    = partial + NBLK;                      // NBLK

  ushort_t* Ub = (ushort_t*)tmpU;                     // bf16 U
  ushort_t* Vb = (ushort_t*)Vbuf;                     // bf16 V
  ushort_t* hB = (ushort_t*)Vbuf + (size_t)NN*HD;     // bf16 h shadow

  // --- decode edge_index + dst histogram ---
  hipMemsetAsync(flag, 0, sizeof(int), stream);
  hipMemsetAsync(counts, 0, NN*sizeof(int), stream);
  detect_kernel<<<DET_SAMPLES/256, 256, 0, stream>>>((const unsigned int*)ei, flag);
  extract_kernel<<<(NE + 255)/256, 256, 0, stream>>>(ei, flag, srcW, dstW, counts);

  // --- CSR: hierarchical exclusive scan + fill (with CSR-ordered src) ---
  scanA_kernel<<<NBLK, 256, 0, stream>>>(counts, partial);
  scanB_kernel<<<1, 256, 0, stream>>>(partial, bOff);
  scanC_kernel<<<NBLK, 256, 0, stream>>>(counts, bOff, row_start, cursor);
  fill_kernel<<<(NE + 255)/256, 256, 0, stream>>>(dstW, srcW, cursor, eids, srcS);

  // h = relu(nf@Wemb+bemb): f32 + bf16 shadow
  gemm_h<<<GGRID, 256, 0, stream>>>(nf, Wemb, bemb, hA, hB, NN, 1);

  for (int L = 0; L < 3; ++L){
    float* hnext = (L < 2) ? hA : hOut;               // h-gemm in-place for L<2
    ushort_t* hBnext = (L < 2) ? hB : nullptr;
    float* mOut = (L < 2) ? nullptr : maskOut;
    gemm_uv<<<GGRID, 256, 0, stream>>>(hA, Wm1, Wm1 + HD*HD, bm1, Ub, Vb, NN);
    mask_msg_kernel<<<NN/4, 256, 0, stream>>>(hA, Ub, Vb, hB, srcS, eids, row_start,
                                              Wm2, bm2, mOut);
    gemm_h<<<GGRID, 256, 0, stream>>>(hA, Wgnn + (size_t)L*HD*HD, bgnn + (size_t)L*HD,
                                      hnext, hBnext, NN, 1);
  }

  pred_kernel<<<1, 128, 0, stream>>>(hOut, Wp1, bp1, Wp2, bp2, predOut);
}